// Round 5
// baseline (382.135 us; speedup 1.0000x reference)
//
#include <hip/hip_runtime.h>

// WordAttention: B=8, S=2048, D_IN=D_H=512, fp32 in/out.
// R5: flash-style fused attention (no S materialization).
// Pipeline (4 dispatches): convx (fp32->fp16), convw (W^T fp16),
// fused QKV GEMM (Q,K token-major fp16; V written transposed as VT[b][d][s]),
// flash kernel: per 64-row Q-tile, online-softmax over 32 key-tiles of 64,
// K/V staged via global_load_lds with XOR-swizzled LDS chunks, P passed
// wave-locally through LDS, O in regs (fp32), normalize at end.

typedef __attribute__((ext_vector_type(8))) _Float16 f16x8;
typedef __attribute__((ext_vector_type(4))) float f32x4;

__device__ __forceinline__ unsigned short f2h(float f) {
  _Float16 h = (_Float16)f;
  return *(unsigned short*)&h;
}

__device__ __forceinline__ void load_lds16(const void* g, void* l) {
  __builtin_amdgcn_global_load_lds(
      (const __attribute__((address_space(1))) unsigned int*)g,
      (__attribute__((address_space(3))) unsigned int*)l, 16, 0, 0);
}

// ---- x fp32 -> fp16 ----
__global__ __launch_bounds__(256) void convx_kernel(const float* __restrict__ x,
                                                    unsigned short* __restrict__ xh) {
  int i = blockIdx.x * 256 + threadIdx.x;
  float4 v = ((const float4*)x)[i];
  union { unsigned short h[4]; short4 s4; } u;
  u.h[0] = f2h(v.x); u.h[1] = f2h(v.y); u.h[2] = f2h(v.z); u.h[3] = f2h(v.w);
  ((short4*)xh)[i] = u.s4;
}

// ---- W [d][h] fp32 -> Wt [h][d] fp16; z = 0,1,2 selects Wq/Wk/Wv ----
__global__ __launch_bounds__(256) void convw_kernel(
    const float* __restrict__ W0, const float* __restrict__ W1,
    const float* __restrict__ W2, unsigned short* __restrict__ Wt) {
  const float* W = (blockIdx.z == 0) ? W0 : (blockIdx.z == 1) ? W1 : W2;
  unsigned short* t = Wt + (size_t)blockIdx.z * 512 * 512;
  __shared__ float tile[32][33];
  int tx = threadIdx.x, ty = threadIdx.y;  // 32 x 8
  int h0 = blockIdx.x * 32, d0 = blockIdx.y * 32;
  for (int i = ty; i < 32; i += 8) tile[i][tx] = W[(long)(d0 + i) * 512 + h0 + tx];
  __syncthreads();
  for (int i = ty; i < 32; i += 8)
    t[(long)(h0 + i) * 512 + d0 + tx] = f2h(tile[tx][i]);
}

// ---- fused QKV projection: [16384,512] x [512,1536]^T + bias.
//      cols 0..511 -> Qo[token][512]; 512..1023 -> Ko[token][512];
//      1024..1535 -> VTo[b][col-1024][s] (transposed write). fp16 out.
__global__ __launch_bounds__(256) void gemm_qkv_kernel(
    const unsigned short* __restrict__ A,   // xh [16384][512]
    const unsigned short* __restrict__ Bt,  // Wt [1536][512]
    unsigned short* __restrict__ Qo, unsigned short* __restrict__ Ko,
    unsigned short* __restrict__ VTo,
    const float* __restrict__ bq, const float* __restrict__ bk,
    const float* __restrict__ bv) {
  __shared__ alignas(16) unsigned short As[128 * 32];
  __shared__ alignas(16) unsigned short Bs[128 * 32];
  const int t = threadIdx.x;
  const long long bm = (long long)blockIdx.x * 128;
  const long long bn = (long long)blockIdx.y * 128;

  const int ar = t >> 2;
  const int ac = (t & 3) * 8;

  f32x4 acc[4][4];
#pragma unroll
  for (int i = 0; i < 4; i++)
#pragma unroll
    for (int j = 0; j < 4; j++) acc[i][j] = {0.f, 0.f, 0.f, 0.f};

  const int lane = t & 63;
  const int wave = t >> 6;
  const int wm = (wave & 1) * 64;
  const int wn = (wave >> 1) * 64;
  const int fm = lane & 15;
  const int k8 = (lane >> 4) * 8;

  for (int kt = 0; kt < 512; kt += 32) {
#pragma unroll
    for (int r = 0; r < 2; r++)
      load_lds16(A + (bm + r * 64 + ar) * 512 + kt + ac, &As[r * 2048 + t * 8]);
#pragma unroll
    for (int r = 0; r < 2; r++)
      load_lds16(Bt + (bn + r * 64 + ar) * 512 + kt + ac, &Bs[r * 2048 + t * 8]);
    __syncthreads();

    f16x8 af[4], bfr[4];
#pragma unroll
    for (int i = 0; i < 4; i++)
      af[i] = *(const f16x8*)&As[(wm + i * 16 + fm) * 32 + k8];
#pragma unroll
    for (int j = 0; j < 4; j++)
      bfr[j] = *(const f16x8*)&Bs[(wn + j * 16 + fm) * 32 + k8];
#pragma unroll
    for (int i = 0; i < 4; i++)
#pragma unroll
      for (int j = 0; j < 4; j++)
        acc[i][j] = __builtin_amdgcn_mfma_f32_16x16x32_f16(af[i], bfr[j], acc[i][j], 0, 0, 0);
    __syncthreads();
  }

  const int crow = (lane >> 4) * 4;  // C/D: col=lane&15, row=(lane>>4)*4+reg
  const int ccol = lane & 15;
#pragma unroll
  for (int j = 0; j < 4; j++) {
    const long long col = bn + wn + j * 16 + ccol;
    float bias = (col < 512) ? bq[col] : (col < 1024) ? bk[col - 512] : bv[col - 1024];
#pragma unroll
    for (int i = 0; i < 4; i++) {
      const long long row0 = bm + wm + i * 16 + crow;
      if (col >= 1024) {
        // VT[b][col-1024][s], s = row0..row0+3 consecutive within one batch
        const long long b = row0 >> 11;
        const long long s = row0 & 2047;
        union { unsigned short h[4]; short4 s4; } u;
#pragma unroll
        for (int r = 0; r < 4; r++) u.h[r] = f2h(acc[i][j][r] + bias);
        *(short4*)(VTo + (b * 512 + (col - 1024)) * 2048 + s) = u.s4;
      } else {
        unsigned short* dst = (col < 512) ? (Qo + row0 * 512 + col)
                                          : (Ko + row0 * 512 + (col - 512));
#pragma unroll
        for (int r = 0; r < 4; r++) dst[(size_t)r * 512] = f2h(acc[i][j][r] + bias);
      }
    }
  }
}

// ---- flash attention: out[b][q][d] = softmax(Q K^T) V, per 64-row Q tile ----
// grid (32, 8): blockIdx.x = q-tile, blockIdx.y = batch. 256 thr / 4 waves.
// Wave w owns q-rows [16w,16w+16): computes St rows via QK^T, consumes its own
// P rows for PV (wave-local LDS round trip, no barrier).
__global__ __launch_bounds__(256, 1) void flash_kernel(
    const unsigned short* __restrict__ Qg,  // [B*S][512] fp16
    const unsigned short* __restrict__ Kg,  // [B*S][512] fp16
    const unsigned short* __restrict__ Vt,  // [B][512][S] fp16
    float* __restrict__ out) {              // [B][S][512] fp32
  // XOR-swizzled chunk layouts (chunk = 8 fp16 = 16 B):
  //   Kb logical [row<64][c8<16] -> phys chunk row*16 + (c8 ^ (row&15))
  //   Vb logical [row<128][c8<8] -> phys chunk row*8  + (c8 ^ (row&7))
  __shared__ alignas(16) unsigned short Kb[64 * 128];
  __shared__ alignas(16) unsigned short Vb[128 * 64];
  __shared__ alignas(16) unsigned short Pt[64 * 68];  // padded, plain layout

  const int t = threadIdx.x;
  const int lane = t & 63;
  const int wave = t >> 6;
  const int quad = lane >> 4;
  const int l15 = lane & 15;
  const int wm = wave * 16;
  const int q0 = blockIdx.x * 64;
  const int b = blockIdx.y;

  const unsigned short* Qb = Qg + ((size_t)b * 2048 + q0) * 512;
  const unsigned short* Kbase = Kg + (size_t)b * 2048 * 512;
  const unsigned short* Vbase = Vt + (size_t)b * 512 * 2048;

  // ---- preload Q fragments (resident): qf[dc*4+kc], d = (dc*4+kc)*32 .. +32
  f16x8 qf[16];
  for (int dc = 0; dc < 4; dc++) {
#pragma unroll
    for (int r = 0; r < 4; r++)
      load_lds16(Qb + (size_t)(r * 16 + (t >> 4)) * 512 + dc * 128 + ((t & 15) ^ (t >> 4)) * 8,
                 &Kb[r * 2048 + t * 8]);
    __syncthreads();
#pragma unroll
    for (int kc = 0; kc < 4; kc++)
      qf[dc * 4 + kc] =
          *(const f16x8*)&Kb[(((wm + l15) << 4) + ((kc * 4 + quad) ^ l15)) * 8];
    __syncthreads();
  }

  f32x4 O[32];
#pragma unroll
  for (int j = 0; j < 32; j++) O[j] = {0.f, 0.f, 0.f, 0.f};
  float m_[4] = {-1e30f, -1e30f, -1e30f, -1e30f};
  float l_[4] = {0.f, 0.f, 0.f, 0.f};

  for (int kt = 0; kt < 2048; kt += 64) {
    // ---- K phase: St[n] (16 q-rows x 64 keys per wave), d in 4 chunks of 128
    f32x4 St[4];
#pragma unroll
    for (int n = 0; n < 4; n++) St[n] = {0.f, 0.f, 0.f, 0.f};
    for (int dc = 0; dc < 4; dc++) {
#pragma unroll
      for (int r = 0; r < 4; r++)
        load_lds16(Kbase + (size_t)(kt + r * 16 + (t >> 4)) * 512 + dc * 128 +
                       ((t & 15) ^ (t >> 4)) * 8,
                   &Kb[r * 2048 + t * 8]);
      __syncthreads();
#pragma unroll
      for (int kc = 0; kc < 4; kc++) {
#pragma unroll
        for (int n = 0; n < 4; n++) {
          f16x8 kf =
              *(const f16x8*)&Kb[(((n * 16 + l15) << 4) + ((kc * 4 + quad) ^ l15)) * 8];
          St[n] = __builtin_amdgcn_mfma_f32_16x16x32_f16(qf[dc * 4 + kc], kf, St[n], 0, 0, 0);
        }
      }
      if (dc < 3) __syncthreads();  // Kb reuse next dc; last dc covered by V barriers
    }

    // ---- online softmax update (rows wm + quad*4 + r; stats across 16 lanes)
    float mt[4], al[4], p[4][4], rs[4];
#pragma unroll
    for (int r = 0; r < 4; r++)
      mt[r] = fmaxf(fmaxf(St[0][r], St[1][r]), fmaxf(St[2][r], St[3][r]));
#pragma unroll
    for (int off = 1; off < 16; off <<= 1)
#pragma unroll
      for (int r = 0; r < 4; r++) mt[r] = fmaxf(mt[r], __shfl_xor(mt[r], off));
    bool upd = false;
#pragma unroll
    for (int r = 0; r < 4; r++) {
      float mn = fmaxf(m_[r], mt[r]);
      al[r] = __expf(m_[r] - mn);
      if (mn > m_[r]) upd = true;
      m_[r] = mn;
      float s = 0.f;
#pragma unroll
      for (int n = 0; n < 4; n++) {
        p[n][r] = __expf(St[n][r] - mn);
        s += p[n][r];
      }
      rs[r] = s;
    }
#pragma unroll
    for (int off = 1; off < 16; off <<= 1)
#pragma unroll
      for (int r = 0; r < 4; r++) rs[r] += __shfl_xor(rs[r], off);
#pragma unroll
    for (int r = 0; r < 4; r++) l_[r] = l_[r] * al[r] + rs[r];
    if (__any(upd)) {  // rescale O only when some row max moved (~ln(32) times)
#pragma unroll
      for (int j = 0; j < 32; j++) {
        f32x4 o = O[j];
        o[0] *= al[0]; o[1] *= al[1]; o[2] *= al[2]; o[3] *= al[3];
        O[j] = o;
      }
    }

    // ---- P to LDS (wave-local rows -> no barrier), pull A-frags
#pragma unroll
    for (int n = 0; n < 4; n++)
#pragma unroll
      for (int r = 0; r < 4; r++)
        Pt[(wm + quad * 4 + r) * 68 + n * 16 + l15] = f2h(p[n][r]);
    f16x8 pf[2];
#pragma unroll
    for (int kc = 0; kc < 2; kc++)
      pf[kc] = *(const f16x8*)&Pt[(wm + l15) * 68 + kc * 32 + quad * 8];

    // ---- V phase: O[dc*8+dt] += P * V, d in 4 chunks of 128
    for (int dc = 0; dc < 4; dc++) {
#pragma unroll
      for (int r = 0; r < 4; r++)
        load_lds16(Vbase + (size_t)(dc * 128 + r * 32 + (t >> 3)) * 2048 + kt +
                       ((t & 7) ^ ((t >> 3) & 7)) * 8,
                   &Vb[r * 2048 + t * 8]);
      __syncthreads();
#pragma unroll
      for (int dt = 0; dt < 8; dt++) {
#pragma unroll
        for (int kc = 0; kc < 2; kc++) {
          f16x8 vf =
              *(const f16x8*)&Vb[(((dt * 16 + l15) << 3) + ((kc * 4 + quad) ^ (l15 & 7))) * 8];
          O[dc * 8 + dt] =
              __builtin_amdgcn_mfma_f32_16x16x32_f16(pf[kc], vf, O[dc * 8 + dt], 0, 0, 0);
        }
      }
      if (dc < 3) __syncthreads();  // Vb reuse next dc; last covered by next-iter K barriers
    }
  }

  // ---- epilogue: out = O / l
  float invl[4];
#pragma unroll
  for (int r = 0; r < 4; r++) invl[r] = 1.0f / l_[r];
  float* ob = out + ((size_t)b * 2048 + q0 + wm + quad * 4) * 512 + l15;
#pragma unroll
  for (int j = 0; j < 32; j++)
#pragma unroll
    for (int r = 0; r < 4; r++)
      ob[(size_t)r * 512 + j * 16] = O[j][r] * invl[r];
}

extern "C" void kernel_launch(void* const* d_in, const int* in_sizes, int n_in,
                              void* d_out, int out_size, void* d_ws, size_t ws_size,
                              hipStream_t stream) {
  const float* x  = (const float*)d_in[0];
  const float* Wq = (const float*)d_in[1];
  const float* bq = (const float*)d_in[2];
  const float* Wk = (const float*)d_in[3];
  const float* bk = (const float*)d_in[4];
  const float* Wv = (const float*)d_in[5];
  const float* bv = (const float*)d_in[6];
  float* out = (float*)d_out;

  const size_t SZ = (size_t)16384 * 512 * 2;  // 16.78 MB (fp16 [16384,512])
  char* p = (char*)d_ws;
  unsigned short* xh = (unsigned short*)p; p += SZ;
  unsigned short* Wt = (unsigned short*)p; p += (size_t)3 * 512 * 512 * 2;
  unsigned short* Qb = (unsigned short*)p; p += SZ;  // [token][512]
  unsigned short* Kb = (unsigned short*)p; p += SZ;  // [token][512]
  unsigned short* VT = (unsigned short*)p; p += SZ;  // [b][512][2048]

  convx_kernel<<<8192, 256, 0, stream>>>(x, xh);
  convw_kernel<<<dim3(16, 16, 3), dim3(32, 8), 0, stream>>>(Wq, Wk, Wv, Wt);
  gemm_qkv_kernel<<<dim3(128, 12), 256, 0, stream>>>(xh, Wt, Qb, Kb, VT, bq, bk, bv);
  flash_kernel<<<dim3(32, 8), 256, 0, stream>>>(Qb, Kb, VT, out);
}

// Round 6
// 304.625 us; speedup vs baseline: 1.2544x; 1.2544x over previous
//
#include <hip/hip_runtime.h>

// WordAttention: B=8, S=2048, D_IN=D_H=512, fp32 in/out.
// R6: flash attention with 2-way split-K (flash-decoding) + combine pass.
//  - grid 32x8x2 = 512 blocks, __launch_bounds__(256,2) -> 2 blocks/CU for
//    inter-block latency hiding (R5 had 1 block/CU -> 87% stall).
//  - double-buffered K/V LDS chunks; loads issued AFTER each barrier and
//    consumed at the NEXT barrier, so the vmcnt(0) barrier drain waits on
//    loads that already had a full compute phase to land.
// 5 dispatches: convx, convw, fused QKV GEMM, flash(split), combine.

typedef __attribute__((ext_vector_type(8))) _Float16 f16x8;
typedef __attribute__((ext_vector_type(4))) float f32x4;

__device__ __forceinline__ unsigned short f2h(float f) {
  _Float16 h = (_Float16)f;
  return *(unsigned short*)&h;
}

__device__ __forceinline__ void load_lds16(const void* g, void* l) {
  __builtin_amdgcn_global_load_lds(
      (const __attribute__((address_space(1))) unsigned int*)g,
      (__attribute__((address_space(3))) unsigned int*)l, 16, 0, 0);
}

// ---- x fp32 -> fp16 ----
__global__ __launch_bounds__(256) void convx_kernel(const float* __restrict__ x,
                                                    unsigned short* __restrict__ xh) {
  int i = blockIdx.x * 256 + threadIdx.x;
  float4 v = ((const float4*)x)[i];
  union { unsigned short h[4]; short4 s4; } u;
  u.h[0] = f2h(v.x); u.h[1] = f2h(v.y); u.h[2] = f2h(v.z); u.h[3] = f2h(v.w);
  ((short4*)xh)[i] = u.s4;
}

// ---- W [d][h] fp32 -> Wt [h][d] fp16; z = 0,1,2 selects Wq/Wk/Wv ----
__global__ __launch_bounds__(256) void convw_kernel(
    const float* __restrict__ W0, const float* __restrict__ W1,
    const float* __restrict__ W2, unsigned short* __restrict__ Wt) {
  const float* W = (blockIdx.z == 0) ? W0 : (blockIdx.z == 1) ? W1 : W2;
  unsigned short* t = Wt + (size_t)blockIdx.z * 512 * 512;
  __shared__ float tile[32][33];
  int tx = threadIdx.x, ty = threadIdx.y;  // 32 x 8
  int h0 = blockIdx.x * 32, d0 = blockIdx.y * 32;
  for (int i = ty; i < 32; i += 8) tile[i][tx] = W[(long)(d0 + i) * 512 + h0 + tx];
  __syncthreads();
  for (int i = ty; i < 32; i += 8)
    t[(long)(h0 + i) * 512 + d0 + tx] = f2h(tile[tx][i]);
}

// ---- fused QKV projection: [16384,512] x [512,1536]^T + bias. ----
__global__ __launch_bounds__(256) void gemm_qkv_kernel(
    const unsigned short* __restrict__ A,   // xh [16384][512]
    const unsigned short* __restrict__ Bt,  // Wt [1536][512]
    unsigned short* __restrict__ Qo, unsigned short* __restrict__ Ko,
    unsigned short* __restrict__ VTo,
    const float* __restrict__ bq, const float* __restrict__ bk,
    const float* __restrict__ bv) {
  __shared__ alignas(16) unsigned short As[128 * 32];
  __shared__ alignas(16) unsigned short Bs[128 * 32];
  const int t = threadIdx.x;
  const long long bm = (long long)blockIdx.x * 128;
  const long long bn = (long long)blockIdx.y * 128;

  const int ar = t >> 2;
  const int ac = (t & 3) * 8;

  f32x4 acc[4][4];
#pragma unroll
  for (int i = 0; i < 4; i++)
#pragma unroll
    for (int j = 0; j < 4; j++) acc[i][j] = {0.f, 0.f, 0.f, 0.f};

  const int lane = t & 63;
  const int wave = t >> 6;
  const int wm = (wave & 1) * 64;
  const int wn = (wave >> 1) * 64;
  const int fm = lane & 15;
  const int k8 = (lane >> 4) * 8;

  for (int kt = 0; kt < 512; kt += 32) {
#pragma unroll
    for (int r = 0; r < 2; r++)
      load_lds16(A + (bm + r * 64 + ar) * 512 + kt + ac, &As[r * 2048 + t * 8]);
#pragma unroll
    for (int r = 0; r < 2; r++)
      load_lds16(Bt + (bn + r * 64 + ar) * 512 + kt + ac, &Bs[r * 2048 + t * 8]);
    __syncthreads();

    f16x8 af[4], bfr[4];
#pragma unroll
    for (int i = 0; i < 4; i++)
      af[i] = *(const f16x8*)&As[(wm + i * 16 + fm) * 32 + k8];
#pragma unroll
    for (int j = 0; j < 4; j++)
      bfr[j] = *(const f16x8*)&Bs[(wn + j * 16 + fm) * 32 + k8];
#pragma unroll
    for (int i = 0; i < 4; i++)
#pragma unroll
      for (int j = 0; j < 4; j++)
        acc[i][j] = __builtin_amdgcn_mfma_f32_16x16x32_f16(af[i], bfr[j], acc[i][j], 0, 0, 0);
    __syncthreads();
  }

  const int crow = (lane >> 4) * 4;  // C/D: col=lane&15, row=(lane>>4)*4+reg
  const int ccol = lane & 15;
#pragma unroll
  for (int j = 0; j < 4; j++) {
    const long long col = bn + wn + j * 16 + ccol;
    float bias = (col < 512) ? bq[col] : (col < 1024) ? bk[col - 512] : bv[col - 1024];
#pragma unroll
    for (int i = 0; i < 4; i++) {
      const long long row0 = bm + wm + i * 16 + crow;
      if (col >= 1024) {
        const long long b = row0 >> 11;
        const long long s = row0 & 2047;
        union { unsigned short h[4]; short4 s4; } u;
#pragma unroll
        for (int r = 0; r < 4; r++) u.h[r] = f2h(acc[i][j][r] + bias);
        *(short4*)(VTo + (b * 512 + (col - 1024)) * 2048 + s) = u.s4;
      } else {
        unsigned short* dst = (col < 512) ? (Qo + row0 * 512 + col)
                                          : (Ko + row0 * 512 + (col - 512));
#pragma unroll
        for (int r = 0; r < 4; r++) dst[(size_t)r * 512] = f2h(acc[i][j][r] + bias);
      }
    }
  }
}

// ---- flash attention, 2-way split over keys. grid (32, 8, 2).
// Per block: 64 q-rows, 1024 keys (split half), online softmax, unnormalized
// partial O + (m,l) written to workspace. Wave w owns q-rows [16w,16w+16).
__global__ __launch_bounds__(256, 2) void flash_kernel(
    const unsigned short* __restrict__ Qg,  // [B*S][512] fp16
    const unsigned short* __restrict__ Kg,  // [B*S][512] fp16
    const unsigned short* __restrict__ Vt,  // [B][512][S] fp16
    float* __restrict__ Opart,              // [2][B*S][512] fp32 (unnormalized)
    float* __restrict__ mlpart) {           // [2][B*S][2] fp32 (m, l)
  // XOR-swizzled chunk layouts (chunk = 8 fp16 = 16 B):
  //   Kb logical [row<64][c8<16] -> phys chunk row*16 + (c8 ^ (row&15))
  //   Vb logical [row<128][c8<8] -> phys chunk row*8  + (c8 ^ (row&7))
  __shared__ alignas(16) unsigned short Kb[2][64 * 128];
  __shared__ alignas(16) unsigned short Vb[2][128 * 64];
  __shared__ alignas(16) unsigned short Pt[64 * 68];  // padded, plain layout

  const int t = threadIdx.x;
  const int lane = t & 63;
  const int wave = t >> 6;
  const int quad = lane >> 4;
  const int l15 = lane & 15;
  const int wm = wave * 16;
  const int q0 = blockIdx.x * 64;
  const int b = blockIdx.y;
  const int split = blockIdx.z;
  const int kbeg = split * 1024;

  const unsigned short* Qb_ = Qg + ((size_t)b * 2048 + q0) * 512;
  const unsigned short* Kbase = Kg + (size_t)b * 2048 * 512;
  const unsigned short* Vbase = Vt + (size_t)b * 512 * 2048;

  // ---- preload Q fragments (resident): qf[dc*4+kc]
  f16x8 qf[16];
  for (int dc = 0; dc < 4; dc++) {
#pragma unroll
    for (int r = 0; r < 4; r++)
      load_lds16(Qb_ + (size_t)(r * 16 + (t >> 4)) * 512 + dc * 128 + ((t & 15) ^ (t >> 4)) * 8,
                 &Kb[0][r * 2048 + t * 8]);
    __syncthreads();
#pragma unroll
    for (int kc = 0; kc < 4; kc++)
      qf[dc * 4 + kc] =
          *(const f16x8*)&Kb[0][(((wm + l15) << 4) + ((kc * 4 + quad) ^ l15)) * 8];
    __syncthreads();
  }
  // issue first K chunk (kt=kbeg, dc=0) -> Kb[0]; consumed at first K barrier
#pragma unroll
  for (int r = 0; r < 4; r++)
    load_lds16(Kbase + (size_t)(kbeg + r * 16 + (t >> 4)) * 512 + ((t & 15) ^ (t >> 4)) * 8,
               &Kb[0][r * 2048 + t * 8]);

  f32x4 O[32];
#pragma unroll
  for (int j = 0; j < 32; j++) O[j] = {0.f, 0.f, 0.f, 0.f};
  float m_[4] = {-1e30f, -1e30f, -1e30f, -1e30f};
  float l_[4] = {0.f, 0.f, 0.f, 0.f};

  for (int kt = kbeg; kt < kbeg + 1024; kt += 64) {
    // ---- K phase: St (16 q-rows x 64 keys per wave), d in 4 chunks of 128
    f32x4 St[4];
#pragma unroll
    for (int n = 0; n < 4; n++) St[n] = {0.f, 0.f, 0.f, 0.f};
    for (int dc = 0; dc < 4; dc++) {
      __syncthreads();  // drains loads issued one phase ago
      if (dc < 3) {
#pragma unroll
        for (int r = 0; r < 4; r++)
          load_lds16(Kbase + (size_t)(kt + r * 16 + (t >> 4)) * 512 + (dc + 1) * 128 +
                         ((t & 15) ^ (t >> 4)) * 8,
                     &Kb[(dc + 1) & 1][r * 2048 + t * 8]);
      } else {
#pragma unroll
        for (int r = 0; r < 4; r++)
          load_lds16(Vbase + (size_t)(r * 32 + (t >> 3)) * 2048 + kt +
                         ((t & 7) ^ ((t >> 3) & 7)) * 8,
                     &Vb[0][r * 2048 + t * 8]);
      }
      const unsigned short* kb = Kb[dc & 1];
#pragma unroll
      for (int kc = 0; kc < 4; kc++) {
#pragma unroll
        for (int n = 0; n < 4; n++) {
          f16x8 kf =
              *(const f16x8*)&kb[(((n * 16 + l15) << 4) + ((kc * 4 + quad) ^ l15)) * 8];
          St[n] = __builtin_amdgcn_mfma_f32_16x16x32_f16(qf[dc * 4 + kc], kf, St[n], 0, 0, 0);
        }
      }
    }

    // ---- online softmax update (rows wm + quad*4 + r; stats across 16 lanes)
    float mt[4], al[4], p[4][4], rs[4];
#pragma unroll
    for (int r = 0; r < 4; r++)
      mt[r] = fmaxf(fmaxf(St[0][r], St[1][r]), fmaxf(St[2][r], St[3][r]));
#pragma unroll
    for (int off = 1; off < 16; off <<= 1)
#pragma unroll
      for (int r = 0; r < 4; r++) mt[r] = fmaxf(mt[r], __shfl_xor(mt[r], off));
    bool upd = false;
#pragma unroll
    for (int r = 0; r < 4; r++) {
      float mn = fmaxf(m_[r], mt[r]);
      al[r] = __expf(m_[r] - mn);
      if (mn > m_[r]) upd = true;
      m_[r] = mn;
      float s = 0.f;
#pragma unroll
      for (int n = 0; n < 4; n++) {
        p[n][r] = __expf(St[n][r] - mn);
        s += p[n][r];
      }
      rs[r] = s;
    }
#pragma unroll
    for (int off = 1; off < 16; off <<= 1)
#pragma unroll
      for (int r = 0; r < 4; r++) rs[r] += __shfl_xor(rs[r], off);
#pragma unroll
    for (int r = 0; r < 4; r++) l_[r] = l_[r] * al[r] + rs[r];
    if (__any(upd)) {
#pragma unroll
      for (int j = 0; j < 32; j++) {
        f32x4 o = O[j];
        o[0] *= al[0]; o[1] *= al[1]; o[2] *= al[2]; o[3] *= al[3];
        O[j] = o;
      }
    }

    // ---- P to LDS (wave-local rows -> no barrier), pull A-frags
#pragma unroll
    for (int n = 0; n < 4; n++)
#pragma unroll
      for (int r = 0; r < 4; r++)
        Pt[(wm + quad * 4 + r) * 68 + n * 16 + l15] = f2h(p[n][r]);
    f16x8 pf[2];
#pragma unroll
    for (int kc = 0; kc < 2; kc++)
      pf[kc] = *(const f16x8*)&Pt[(wm + l15) * 68 + kc * 32 + quad * 8];

    // ---- V phase: O += P * V, d in 4 chunks of 128
    for (int dc = 0; dc < 4; dc++) {
      __syncthreads();  // drains loads issued one phase ago
      if (dc < 3) {
#pragma unroll
        for (int r = 0; r < 4; r++)
          load_lds16(Vbase + (size_t)((dc + 1) * 128 + r * 32 + (t >> 3)) * 2048 + kt +
                         ((t & 7) ^ ((t >> 3) & 7)) * 8,
                     &Vb[(dc + 1) & 1][r * 2048 + t * 8]);
      } else if (kt + 64 < kbeg + 1024) {
#pragma unroll
        for (int r = 0; r < 4; r++)
          load_lds16(Kbase + (size_t)(kt + 64 + r * 16 + (t >> 4)) * 512 +
                         ((t & 15) ^ (t >> 4)) * 8,
                     &Kb[0][r * 2048 + t * 8]);
      }
      const unsigned short* vb = Vb[dc & 1];
#pragma unroll
      for (int dt = 0; dt < 8; dt++) {
#pragma unroll
        for (int kc = 0; kc < 2; kc++) {
          f16x8 vf =
              *(const f16x8*)&vb[(((dt * 16 + l15) << 3) + ((kc * 4 + quad) ^ (l15 & 7))) * 8];
          O[dc * 8 + dt] =
              __builtin_amdgcn_mfma_f32_16x16x32_f16(pf[kc], vf, O[dc * 8 + dt], 0, 0, 0);
        }
      }
    }
  }

  // ---- epilogue: write unnormalized partial O and (m, l)
  const size_t rowbase = (size_t)b * 2048 + q0 + wm + quad * 4;
  float* Ob = Opart + (size_t)split * 16384 * 512 + rowbase * 512 + l15;
#pragma unroll
  for (int j = 0; j < 32; j++)
#pragma unroll
    for (int r = 0; r < 4; r++)
      Ob[(size_t)r * 512 + j * 16] = O[j][r];
  if (l15 == 0) {
#pragma unroll
    for (int r = 0; r < 4; r++) {
      size_t row = rowbase + r;
      mlpart[((size_t)split * 16384 + row) * 2] = m_[r];
      mlpart[((size_t)split * 16384 + row) * 2 + 1] = l_[r];
    }
  }
}

// ---- combine: out[row] = (O0*e^{m0-m} + O1*e^{m1-m}) / (l0 e^{m0-m} + l1 e^{m1-m})
__global__ __launch_bounds__(128) void combine_kernel(
    const float* __restrict__ Op, const float* __restrict__ ml,
    float* __restrict__ out) {
  const size_t row = blockIdx.x;  // 16384 rows
  const int t = threadIdx.x;      // 128 threads x float4 = 512
  const float m0 = ml[row * 2], l0 = ml[row * 2 + 1];
  const float m1 = ml[(16384 + row) * 2], l1 = ml[(16384 + row) * 2 + 1];
  const float m = fmaxf(m0, m1);
  float w0 = __expf(m0 - m), w1 = __expf(m1 - m);
  const float inv = 1.0f / (l0 * w0 + l1 * w1);
  w0 *= inv; w1 *= inv;
  float4 a = ((const float4*)(Op + row * 512))[t];
  float4 c = ((const float4*)(Op + (size_t)16384 * 512 + row * 512))[t];
  float4 o;
  o.x = a.x * w0 + c.x * w1;
  o.y = a.y * w0 + c.y * w1;
  o.z = a.z * w0 + c.z * w1;
  o.w = a.w * w0 + c.w * w1;
  ((float4*)(out + row * 512))[t] = o;
}

extern "C" void kernel_launch(void* const* d_in, const int* in_sizes, int n_in,
                              void* d_out, int out_size, void* d_ws, size_t ws_size,
                              hipStream_t stream) {
  const float* x  = (const float*)d_in[0];
  const float* Wq = (const float*)d_in[1];
  const float* bq = (const float*)d_in[2];
  const float* Wk = (const float*)d_in[3];
  const float* bk = (const float*)d_in[4];
  const float* Wv = (const float*)d_in[5];
  const float* bv = (const float*)d_in[6];
  float* out = (float*)d_out;

  const size_t SZ = (size_t)16384 * 512 * 2;  // 16.78 MB (fp16 [16384,512])
  char* p = (char*)d_ws;
  unsigned short* xh = (unsigned short*)p; p += SZ;
  unsigned short* Wt = (unsigned short*)p; p += (size_t)3 * 512 * 512 * 2;
  unsigned short* Qb = (unsigned short*)p; p += SZ;  // [token][512]
  unsigned short* Kb = (unsigned short*)p; p += SZ;  // [token][512]
  unsigned short* VT = (unsigned short*)p; p += SZ;  // [b][512][2048]
  float* Opart = (float*)p; p += (size_t)2 * 16384 * 512 * 4;  // 67 MB
  float* mlpart = (float*)p; p += (size_t)2 * 16384 * 2 * 4;   // 256 KB

  convx_kernel<<<8192, 256, 0, stream>>>(x, xh);
  convw_kernel<<<dim3(16, 16, 3), dim3(32, 8), 0, stream>>>(Wq, Wk, Wv, Wt);
  gemm_qkv_kernel<<<dim3(128, 12), 256, 0, stream>>>(xh, Wt, Qb, Kb, VT, bq, bk, bv);
  flash_kernel<<<dim3(32, 8, 2), 256, 0, stream>>>(Qb, Kb, VT, Opart, mlpart);
  combine_kernel<<<16384, 128, 0, stream>>>(Opart, mlpart, out);
}